// Round 2
// baseline (647.186 us; speedup 1.0000x reference)
//
#include <hip/hip_runtime.h>

// SelfAttention B=8 S=2048 D=1024 fp32 -> fp32, bf16 MFMA internally.
// Pipeline (low-ws, no materialized scores):
//   cast(fp32->bf16, xbuf reused) -> 3x proj GEMM (Q,K bf16; V -> Vt transposed)
//   -> S-kernel: QK^T GEMM, epilogue exp(s/32)*mask -> unnormalized bf16 probs
//      + atomic per-row sum (no max-subtraction: |s|<~2, fp32-exact regime)
//   -> PV GEMM, epilogue divides by rowsum -> fp32 out.
// GEMM core = m97-style: 128x128 tile, BK=32, 4 waves, 16x16x32 bf16 MFMA,
// global_load_lds width=16 staging, 2-barrier K-loop.
// Workspace: Qp[0,32M) Kp[32,64M) Vt[64,96M) probs[96,160M) rowsum[160M,+64K)
//            xbuf aliases [96,128M), weights alias [128,134M)  => 160.1 MB.

#define BATCH 8
#define SEQ   2048
#define DM    1024

typedef __bf16 bf16x8 __attribute__((ext_vector_type(8)));
typedef float  f32x4  __attribute__((ext_vector_type(4)));
typedef unsigned short ushort8 __attribute__((ext_vector_type(8)));
typedef unsigned short ushort4v __attribute__((ext_vector_type(4)));

__device__ __forceinline__ unsigned short f2b(float f) {
    unsigned u = __builtin_bit_cast(unsigned, f);
    u += 0x7fffu + ((u >> 16) & 1u);   // round-to-nearest-even
    return (unsigned short)(u >> 16);
}

// ---------------- cast fp32 -> bf16 (8 elems/thread) ----------------
__global__ void cast_bf16(const float* __restrict__ src,
                          unsigned short* __restrict__ dst, int n8) {
    int i = blockIdx.x * blockDim.x + threadIdx.x;
    if (i >= n8) return;
    const f32x4* s4 = (const f32x4*)src;
    f32x4 a = s4[2 * i], b = s4[2 * i + 1];
    ushort8 o;
    o[0] = f2b(a[0]); o[1] = f2b(a[1]); o[2] = f2b(a[2]); o[3] = f2b(a[3]);
    o[4] = f2b(b[0]); o[5] = f2b(b[1]); o[6] = f2b(b[2]); o[7] = f2b(b[3]);
    ((ushort8*)dst)[i] = o;
}

// ---------------- GEMM-BT: C[M,N] = A[M,K] * B[N,K]^T -----------------
// MODE 0: bf16 out + bias                         (Q,K projection)
// MODE 1: bf16 out + bias, write C^T -> Vt[b][n][s]  (V projection)
// MODE 4: scores: p=mask*exp(acc*scale) -> bf16 probs + atomic rowsum
//         (A,B += bz*SEQ*DM)
// MODE 3: PV: fp32 out * (1/rowsum[row])          (A += bz*SEQ*SEQ,
//         B += bz*DM*SEQ)
template <int MODE>
__global__ __launch_bounds__(256) void gemm_bt(
    const unsigned short* __restrict__ Ag,
    const unsigned short* __restrict__ Bg,
    void* __restrict__ Cg, const float* __restrict__ bias,
    int M, int N, int K, float scale,
    const int* __restrict__ mask, float* __restrict__ rowsum) {
    const int bz = blockIdx.z;
    if (MODE == 4) { Ag += (size_t)bz * SEQ * DM;  Bg += (size_t)bz * SEQ * DM; }
    if (MODE == 3) { Ag += (size_t)bz * SEQ * SEQ; Bg += (size_t)bz * DM * SEQ; }

    const int n0 = blockIdx.x * 128;
    const int m0 = blockIdx.y * 128;
    const int tid = threadIdx.x;
    const int wave = tid >> 6, lane = tid & 63;
    const int waveM = wave >> 1, waveN = wave & 1;
    const int quad = lane >> 4, l16 = lane & 15;

    __shared__ __align__(16) unsigned short As[128 * 32];
    __shared__ __align__(16) unsigned short Bs[128 * 32];

    f32x4 acc[4][4] = {};

    // staging: lane i lands at wave-uniform LDS base + i*16B (HW constraint)
    const int sr = lane >> 2;        // 0..15 row-in-group
    const int sc = (lane & 3) * 8;   // 0,8,16,24 ushort offset (16B chunks)
    const unsigned short* gA = Ag + (size_t)(m0 + wave * 32 + sr) * K + sc;
    const unsigned short* gB = Bg + (size_t)(n0 + wave * 32 + sr) * K + sc;
    unsigned short* lA = As + (wave * 32 + sr) * 32 + sc;
    unsigned short* lB = Bs + (wave * 32 + sr) * 32 + sc;

    for (int kt = 0; kt < K; kt += 32) {
        __builtin_amdgcn_global_load_lds(
            (const __attribute__((address_space(1))) void*)(gA + kt),
            (__attribute__((address_space(3))) void*)lA, 16, 0, 0);
        __builtin_amdgcn_global_load_lds(
            (const __attribute__((address_space(1))) void*)(gA + kt + (size_t)16 * K),
            (__attribute__((address_space(3))) void*)(lA + 16 * 32), 16, 0, 0);
        __builtin_amdgcn_global_load_lds(
            (const __attribute__((address_space(1))) void*)(gB + kt),
            (__attribute__((address_space(3))) void*)lB, 16, 0, 0);
        __builtin_amdgcn_global_load_lds(
            (const __attribute__((address_space(1))) void*)(gB + kt + (size_t)16 * K),
            (__attribute__((address_space(3))) void*)(lB + 16 * 32), 16, 0, 0);
        __syncthreads();   // drains vmcnt -> staged tile visible

        bf16x8 af[4], bf[4];
#pragma unroll
        for (int i = 0; i < 4; ++i)
            af[i] = *(const bf16x8*)(As + (waveM * 64 + i * 16 + l16) * 32 + quad * 8);
#pragma unroll
        for (int j = 0; j < 4; ++j)
            bf[j] = *(const bf16x8*)(Bs + (waveN * 64 + j * 16 + l16) * 32 + quad * 8);
#pragma unroll
        for (int i = 0; i < 4; ++i)
#pragma unroll
            for (int j = 0; j < 4; ++j)
                acc[i][j] = __builtin_amdgcn_mfma_f32_16x16x32_bf16(
                    af[i], bf[j], acc[i][j], 0, 0, 0);
        __syncthreads();   // all reads done before next stage overwrites
    }

    // epilogue: C/D layout col=lane&15, row=quad*4+reg  [m89/m91-verified]
    if (MODE == 0) {
        unsigned short* C = (unsigned short*)Cg;
#pragma unroll
        for (int i = 0; i < 4; ++i) {
            const int gmb = m0 + waveM * 64 + i * 16 + quad * 4;
#pragma unroll
            for (int j = 0; j < 4; ++j) {
                const int gn = n0 + waveN * 64 + j * 16 + l16;
                const float bv = bias[gn];
#pragma unroll
                for (int r = 0; r < 4; ++r)
                    C[(size_t)(gmb + r) * N + gn] = f2b(acc[i][j][r] + bv);
            }
        }
    } else if (MODE == 1) {
#pragma unroll
        for (int i = 0; i < 4; ++i) {
            const int gmb = m0 + waveM * 64 + i * 16 + quad * 4;
            const int b = gmb >> 11;       // batch
            const int s = gmb & 2047;      // seq pos (4-aligned)
#pragma unroll
            for (int j = 0; j < 4; ++j) {
                const int gn = n0 + waveN * 64 + j * 16 + l16;
                const float bv = bias[gn];
                ushort4v o;
#pragma unroll
                for (int r = 0; r < 4; ++r) o[r] = f2b(acc[i][j][r] + bv);
                *(ushort4v*)((unsigned short*)Cg + (size_t)b * DM * SEQ +
                             (size_t)gn * SEQ + s) = o;
            }
        }
    } else if (MODE == 4) {
        unsigned short* C = (unsigned short*)Cg + (size_t)bz * SEQ * SEQ;
        const int* mrow = mask + bz * SEQ;
#pragma unroll
        for (int i = 0; i < 4; ++i) {
            const int gmb = m0 + waveM * 64 + i * 16 + quad * 4;
            float rpart[4] = {0.f, 0.f, 0.f, 0.f};
#pragma unroll
            for (int j = 0; j < 4; ++j) {
                const int gn = n0 + waveN * 64 + j * 16 + l16;
                const float mv = (mrow[gn] != 0) ? 1.0f : 0.0f;
#pragma unroll
                for (int r = 0; r < 4; ++r) {
                    const float p = mv * __expf(acc[i][j][r] * scale);
                    rpart[r] += p;
                    C[(size_t)(gmb + r) * SEQ + gn] = f2b(p);
                }
            }
#pragma unroll
            for (int r = 0; r < 4; ++r) {
                float s = rpart[r];
                s += __shfl_xor(s, 1, 64);
                s += __shfl_xor(s, 2, 64);
                s += __shfl_xor(s, 4, 64);
                s += __shfl_xor(s, 8, 64);
                if (l16 == 0)
                    atomicAdd(&rowsum[bz * SEQ + gmb + r], s);
            }
        }
    } else {  // MODE 3
        float* C = (float*)Cg + (size_t)bz * SEQ * DM;
#pragma unroll
        for (int i = 0; i < 4; ++i) {
            const int gmb = m0 + waveM * 64 + i * 16 + quad * 4;
            float inv[4];
#pragma unroll
            for (int r = 0; r < 4; ++r)
                inv[r] = 1.0f / rowsum[bz * SEQ + gmb + r];
#pragma unroll
            for (int j = 0; j < 4; ++j) {
                const int gn = n0 + waveN * 64 + j * 16 + l16;
#pragma unroll
                for (int r = 0; r < 4; ++r)
                    C[(size_t)(gmb + r) * N + gn] = acc[i][j][r] * inv[r];
            }
        }
    }
}

extern "C" void kernel_launch(void* const* d_in, const int* in_sizes, int n_in,
                              void* d_out, int out_size, void* d_ws, size_t ws_size,
                              hipStream_t stream) {
    const float* query = (const float*)d_in[0];
    const float* key_  = (const float*)d_in[1];
    const float* value = (const float*)d_in[2];
    const int*   mask  = (const int*)d_in[3];
    const float* Wq = (const float*)d_in[4];
    const float* bq = (const float*)d_in[5];
    const float* Wk = (const float*)d_in[6];
    const float* bk = (const float*)d_in[7];
    const float* Wv = (const float*)d_in[8];
    const float* bv = (const float*)d_in[9];
    float* out = (float*)d_out;

    char* ws = (char*)d_ws;
    const size_t MB = 1024 * 1024;
    unsigned short* Qp    = (unsigned short*)(ws);            // 32MB
    unsigned short* Kp    = (unsigned short*)(ws + 32 * MB);  // 32MB
    unsigned short* Vt    = (unsigned short*)(ws + 64 * MB);  // 32MB
    unsigned short* probs = (unsigned short*)(ws + 96 * MB);  // 64MB
    float* rowsum         = (float*)(ws + 160 * MB);          // 64KB
    // phase-1 aliases (dead before probs is written):
    unsigned short* xbuf = (unsigned short*)(ws + 96 * MB);   // 32MB
    unsigned short* wq   = (unsigned short*)(ws + 128 * MB);  // 2MB
    unsigned short* wk   = (unsigned short*)(ws + 130 * MB);  // 2MB
    unsigned short* wv   = (unsigned short*)(ws + 132 * MB);  // 2MB

    const int NE = BATCH * SEQ * DM;  // 16777216
    const int NW = DM * DM;           // 1048576

    hipMemsetAsync(rowsum, 0, (size_t)BATCH * SEQ * sizeof(float), stream);

    cast_bf16<<<NW / 8 / 256, 256, 0, stream>>>(Wq, wq, NW / 8);
    cast_bf16<<<NW / 8 / 256, 256, 0, stream>>>(Wk, wk, NW / 8);
    cast_bf16<<<NW / 8 / 256, 256, 0, stream>>>(Wv, wv, NW / 8);

    const dim3 blk(256);
    const dim3 gproj(DM / 128, (BATCH * SEQ) / 128, 1);  // 8 x 128

    cast_bf16<<<NE / 8 / 256, 256, 0, stream>>>(query, xbuf, NE / 8);
    gemm_bt<0><<<gproj, blk, 0, stream>>>(xbuf, wq, Qp, bq,
                                          BATCH * SEQ, DM, DM, 1.f, nullptr, nullptr);
    cast_bf16<<<NE / 8 / 256, 256, 0, stream>>>(key_, xbuf, NE / 8);
    gemm_bt<0><<<gproj, blk, 0, stream>>>(xbuf, wk, Kp, bk,
                                          BATCH * SEQ, DM, DM, 1.f, nullptr, nullptr);
    cast_bf16<<<NE / 8 / 256, 256, 0, stream>>>(value, xbuf, NE / 8);
    gemm_bt<1><<<gproj, blk, 0, stream>>>(xbuf, wv, Vt, bv,
                                          BATCH * SEQ, DM, DM, 1.f, nullptr, nullptr);

    // scores + exp + mask + rowsum (no fp32 score materialization)
    gemm_bt<4><<<dim3(SEQ / 128, SEQ / 128, BATCH), blk, 0, stream>>>(
        Qp, Kp, probs, nullptr, SEQ, SEQ, DM, 0.03125f, mask, rowsum);

    // PV with fused 1/rowsum normalization
    gemm_bt<3><<<dim3(DM / 128, SEQ / 128, BATCH), blk, 0, stream>>>(
        probs, Vt, out, nullptr, SEQ, DM, SEQ, 1.f, nullptr, rowsum);
}

// Round 3
// 535.958 us; speedup vs baseline: 1.2075x; 1.2075x over previous
//
#include <hip/hip_runtime.h>

// SelfAttention B=8 S=2048 D=1024 fp32 -> fp32, bf16 MFMA internally.
// R3: mask-compaction. ~50% of keys are masked out; we compact valid key/value
// rows per batch (stable prefix-sum gather) BEFORE projection, halving the
// K-proj, V-proj, scores GEMM, probs traffic, and PV GEMM.
// Pipeline:
//   build_idx (per-batch scan of mask -> idx, cnt, cntp=ceil128(cnt))
//   castW x3; gatherK->xbuf; Kproj->Kc; gatherV->xbuf; Vproj->Vtc (transposed);
//   castQ->xbuf; Qproj->Qp;
//   scores GEMM (N limited to cntp[b]): p = (gn<cnt)? exp(s/32):0 -> bf16 probs
//     + atomic rowsum (no max-subtraction: |s|<~2, fp32-exact regime)
//   PV GEMM (K limited to cntp[b]), epilogue /rowsum -> fp32 out.
// GEMM core = m97-style: 128x128 tile, BK=32, 4 waves, 16x16x32 bf16 MFMA,
// global_load_lds width=16 staging, 2-barrier K-loop.
// Workspace (<=160.2 MB): Qp[0,32M) Kc[32,64M) Vtc[64,96M) probs[96,160M)
//   aliases: xbuf[96,128M), weights[128,134M) (dead before scores)
//   rowsum[160M) idx[+64K) cnt/cntp small.

#define BATCH 8
#define SEQ   2048
#define DM    1024

typedef __bf16 bf16x8 __attribute__((ext_vector_type(8)));
typedef float  f32x4  __attribute__((ext_vector_type(4)));
typedef unsigned short ushort8 __attribute__((ext_vector_type(8)));
typedef unsigned short ushort4v __attribute__((ext_vector_type(4)));

__device__ __forceinline__ unsigned short f2b(float f) {
    unsigned u = __builtin_bit_cast(unsigned, f);
    u += 0x7fffu + ((u >> 16) & 1u);   // round-to-nearest-even
    return (unsigned short)(u >> 16);
}

// ---------------- per-batch mask compaction index ----------------
__global__ __launch_bounds__(256) void build_idx(
    const int* __restrict__ mask, int* __restrict__ idx,
    int* __restrict__ cnt, int* __restrict__ cntp) {
    const int b = blockIdx.x;
    const int* m = mask + b * SEQ;
    const int t = threadIdx.x;
    __shared__ int sums[256];
    int loc[8], s = 0;
#pragma unroll
    for (int u = 0; u < 8; ++u) { loc[u] = (m[t * 8 + u] != 0); s += loc[u]; }
    sums[t] = s;
    __syncthreads();
    // inclusive Hillis-Steele scan
    for (int off = 1; off < 256; off <<= 1) {
        int v = (t >= off) ? sums[t - off] : 0;
        __syncthreads();
        sums[t] += v;
        __syncthreads();
    }
    int base = sums[t] - s;   // exclusive prefix
#pragma unroll
    for (int u = 0; u < 8; ++u)
        if (loc[u]) idx[b * SEQ + base++] = t * 8 + u;
    if (t == 255) {
        cnt[b] = sums[255];
        cntp[b] = (sums[255] + 127) & ~127;
    }
}

// ---------------- cast fp32 -> bf16 (8 elems/thread, plain) ----------
__global__ void cast_bf16(const float* __restrict__ src,
                          unsigned short* __restrict__ dst, int n8) {
    int i = blockIdx.x * blockDim.x + threadIdx.x;
    if (i >= n8) return;
    const f32x4* s4 = (const f32x4*)src;
    f32x4 a = s4[2 * i], b = s4[2 * i + 1];
    ushort8 o;
    o[0] = f2b(a[0]); o[1] = f2b(a[1]); o[2] = f2b(a[2]); o[3] = f2b(a[3]);
    o[4] = f2b(b[0]); o[5] = f2b(b[1]); o[6] = f2b(b[2]); o[7] = f2b(b[3]);
    ((ushort8*)dst)[i] = o;
}

// ---------------- gather valid rows + cast; zero-fill [cnt,cntp) -----
__global__ __launch_bounds__(256) void cast_gather(
    const float* __restrict__ src, unsigned short* __restrict__ dst,
    const int* __restrict__ idx, const int* __restrict__ cnt,
    const int* __restrict__ cntp) {
    const int b = blockIdx.y, j = blockIdx.x;
    if (j >= cntp[b]) return;
    const int t = threadIdx.x;
    unsigned short* drow = dst + ((size_t)b * SEQ + j) * DM;
    if (j < cnt[b]) {
        const float* srow = src + ((size_t)b * SEQ + idx[b * SEQ + j]) * DM;
        f32x4 a = ((const f32x4*)srow)[t];
        ushort4v o;
        o[0] = f2b(a[0]); o[1] = f2b(a[1]); o[2] = f2b(a[2]); o[3] = f2b(a[3]);
        ((ushort4v*)drow)[t] = o;
    } else {
        ushort4v z = {0, 0, 0, 0};
        ((ushort4v*)drow)[t] = z;
    }
}

// ---------------- GEMM-BT: C[M,N] = A[M,K] * B[N,K]^T -----------------
// All modes per-batch via blockIdx.z. cnt/cntp limits per mode:
// MODE 0 (PROJ):  bf16 C+bias; M-limit cntp (nullptr => full).
// MODE 1 (PROJT): bf16 C^T+bias -> C[b][gn][j]; M-limit cntp.
// MODE 4 (SCORES): N-limit cntp; p=(gn<cnt)?exp(acc*scale):0 -> bf16 +
//                  atomic rowsum.
// MODE 3 (PV):    K-limit cntp; fp32 C * (1/rowsum[row]).
template <int MODE>
__global__ __launch_bounds__(256) void gemm_bt(
    const unsigned short* __restrict__ Ag,
    const unsigned short* __restrict__ Bg,
    void* __restrict__ Cg, const float* __restrict__ bias,
    int lda, int ldb, int ldc, int K, float scale,
    float* __restrict__ rowsum,
    const int* __restrict__ cnt, const int* __restrict__ cntp) {
    const int bz = blockIdx.z;
    const int n0 = blockIdx.x * 128;
    const int m0 = blockIdx.y * 128;

    if ((MODE == 0 || MODE == 1) && cntp && m0 >= cntp[bz]) return;
    if (MODE == 4 && n0 >= cntp[bz]) return;

    // per-batch operand bases
    if (MODE == 0 || MODE == 1) {
        Ag += (size_t)bz * SEQ * lda;                 // activations
        // Bg = weights, shared across batches
    } else if (MODE == 4) {
        Ag += (size_t)bz * SEQ * lda;                 // Qp
        Bg += (size_t)bz * SEQ * ldb;                 // Kc
    } else {                                          // MODE 3
        Ag += (size_t)bz * SEQ * lda;                 // probs (ld 2048)
        Bg += (size_t)bz * (size_t)DM * ldb;          // Vtc (ld 2048)
    }
    const int kend = (MODE == 3) ? cntp[bz] : K;

    const int tid = threadIdx.x;
    const int wave = tid >> 6, lane = tid & 63;
    const int waveM = wave >> 1, waveN = wave & 1;
    const int quad = lane >> 4, l16 = lane & 15;

    __shared__ __align__(16) unsigned short As[128 * 32];
    __shared__ __align__(16) unsigned short Bs[128 * 32];

    f32x4 acc[4][4] = {};

    // staging: lane i lands at wave-uniform LDS base + i*16B (HW constraint)
    const int sr = lane >> 2;        // 0..15 row-in-group
    const int sc = (lane & 3) * 8;   // 0,8,16,24 ushort offset (16B chunks)
    const unsigned short* gA = Ag + (size_t)(m0 + wave * 32 + sr) * lda + sc;
    const unsigned short* gB = Bg + (size_t)(n0 + wave * 32 + sr) * ldb + sc;
    unsigned short* lA = As + (wave * 32 + sr) * 32 + sc;
    unsigned short* lB = Bs + (wave * 32 + sr) * 32 + sc;

    for (int kt = 0; kt < kend; kt += 32) {
        __builtin_amdgcn_global_load_lds(
            (const __attribute__((address_space(1))) void*)(gA + kt),
            (__attribute__((address_space(3))) void*)lA, 16, 0, 0);
        __builtin_amdgcn_global_load_lds(
            (const __attribute__((address_space(1))) void*)(gA + kt + (size_t)16 * lda),
            (__attribute__((address_space(3))) void*)(lA + 16 * 32), 16, 0, 0);
        __builtin_amdgcn_global_load_lds(
            (const __attribute__((address_space(1))) void*)(gB + kt),
            (__attribute__((address_space(3))) void*)lB, 16, 0, 0);
        __builtin_amdgcn_global_load_lds(
            (const __attribute__((address_space(1))) void*)(gB + kt + (size_t)16 * ldb),
            (__attribute__((address_space(3))) void*)(lB + 16 * 32), 16, 0, 0);
        __syncthreads();   // drains vmcnt -> staged tile visible

        bf16x8 af[4], bf[4];
#pragma unroll
        for (int i = 0; i < 4; ++i)
            af[i] = *(const bf16x8*)(As + (waveM * 64 + i * 16 + l16) * 32 + quad * 8);
#pragma unroll
        for (int j = 0; j < 4; ++j)
            bf[j] = *(const bf16x8*)(Bs + (waveN * 64 + j * 16 + l16) * 32 + quad * 8);
#pragma unroll
        for (int i = 0; i < 4; ++i)
#pragma unroll
            for (int j = 0; j < 4; ++j)
                acc[i][j] = __builtin_amdgcn_mfma_f32_16x16x32_bf16(
                    af[i], bf[j], acc[i][j], 0, 0, 0);
        __syncthreads();   // all reads done before next stage overwrites
    }

    // epilogue: C/D layout col=lane&15, row=quad*4+reg  [m89/m91-verified]
    if (MODE == 0) {
        unsigned short* C = (unsigned short*)Cg + (size_t)bz * SEQ * ldc;
#pragma unroll
        for (int i = 0; i < 4; ++i) {
            const int gmb = m0 + waveM * 64 + i * 16 + quad * 4;
#pragma unroll
            for (int j = 0; j < 4; ++j) {
                const int gn = n0 + waveN * 64 + j * 16 + l16;
                const float bv = bias[gn];
#pragma unroll
                for (int r = 0; r < 4; ++r)
                    C[(size_t)(gmb + r) * ldc + gn] = f2b(acc[i][j][r] + bv);
            }
        }
    } else if (MODE == 1) {
        unsigned short* C = (unsigned short*)Cg + (size_t)bz * (size_t)DM * SEQ;
#pragma unroll
        for (int i = 0; i < 4; ++i) {
            const int gmb = m0 + waveM * 64 + i * 16 + quad * 4;  // compacted j
#pragma unroll
            for (int j = 0; j < 4; ++j) {
                const int gn = n0 + waveN * 64 + j * 16 + l16;
                const float bv = bias[gn];
                ushort4v o;
#pragma unroll
                for (int r = 0; r < 4; ++r) o[r] = f2b(acc[i][j][r] + bv);
                *(ushort4v*)(C + (size_t)gn * SEQ + gmb) = o;
            }
        }
    } else if (MODE == 4) {
        unsigned short* C = (unsigned short*)Cg + (size_t)bz * SEQ * ldc;
        const int cn = cnt[bz];
#pragma unroll
        for (int i = 0; i < 4; ++i) {
            const int gmb = m0 + waveM * 64 + i * 16 + quad * 4;
            float rpart[4] = {0.f, 0.f, 0.f, 0.f};
#pragma unroll
            for (int j = 0; j < 4; ++j) {
                const int gn = n0 + waveN * 64 + j * 16 + l16;
                const float mv = (gn < cn) ? 1.0f : 0.0f;
#pragma unroll
                for (int r = 0; r < 4; ++r) {
                    const float p = mv * __expf(acc[i][j][r] * scale);
                    rpart[r] += p;
                    C[(size_t)(gmb + r) * ldc + gn] = f2b(p);
                }
            }
#pragma unroll
            for (int r = 0; r < 4; ++r) {
                float s = rpart[r];
                s += __shfl_xor(s, 1, 64);
                s += __shfl_xor(s, 2, 64);
                s += __shfl_xor(s, 4, 64);
                s += __shfl_xor(s, 8, 64);
                if (l16 == 0)
                    atomicAdd(&rowsum[bz * SEQ + gmb + r], s);
            }
        }
    } else {  // MODE 3
        float* C = (float*)Cg + (size_t)bz * SEQ * ldc;
#pragma unroll
        for (int i = 0; i < 4; ++i) {
            const int gmb = m0 + waveM * 64 + i * 16 + quad * 4;
            float inv[4];
#pragma unroll
            for (int r = 0; r < 4; ++r)
                inv[r] = 1.0f / rowsum[bz * SEQ + gmb + r];
#pragma unroll
            for (int j = 0; j < 4; ++j) {
                const int gn = n0 + waveN * 64 + j * 16 + l16;
#pragma unroll
                for (int r = 0; r < 4; ++r)
                    C[(size_t)(gmb + r) * ldc + gn] = acc[i][j][r] * inv[r];
            }
        }
    }
}

extern "C" void kernel_launch(void* const* d_in, const int* in_sizes, int n_in,
                              void* d_out, int out_size, void* d_ws, size_t ws_size,
                              hipStream_t stream) {
    const float* query = (const float*)d_in[0];
    const float* key_  = (const float*)d_in[1];
    const float* value = (const float*)d_in[2];
    const int*   mask  = (const int*)d_in[3];
    const float* Wq = (const float*)d_in[4];
    const float* bq = (const float*)d_in[5];
    const float* Wk = (const float*)d_in[6];
    const float* bk = (const float*)d_in[7];
    const float* Wv = (const float*)d_in[8];
    const float* bv = (const float*)d_in[9];
    float* out = (float*)d_out;

    char* ws = (char*)d_ws;
    const size_t MB = 1024 * 1024;
    unsigned short* Qp    = (unsigned short*)(ws);            // 32MB
    unsigned short* Kc    = (unsigned short*)(ws + 32 * MB);  // 32MB
    unsigned short* Vtc   = (unsigned short*)(ws + 64 * MB);  // 32MB
    unsigned short* probs = (unsigned short*)(ws + 96 * MB);  // 64MB
    // phase-1 aliases inside probs region (dead before scores):
    unsigned short* xbuf = (unsigned short*)(ws + 96 * MB);   // 32MB
    unsigned short* wq   = (unsigned short*)(ws + 128 * MB);  // 2MB
    unsigned short* wk   = (unsigned short*)(ws + 130 * MB);  // 2MB
    unsigned short* wv   = (unsigned short*)(ws + 132 * MB);  // 2MB
    float* rowsum = (float*)(ws + 160 * MB);                  // 64KB
    int*   idx    = (int*)(ws + 160 * MB + 64 * 1024);        // 64KB
    int*   cnt    = (int*)(ws + 160 * MB + 128 * 1024);       // 32B
    int*   cntp   = (int*)(ws + 160 * MB + 128 * 1024 + 64);  // 32B

    const int NE = BATCH * SEQ * DM;  // 16777216
    const int NW = DM * DM;           // 1048576

    hipMemsetAsync(rowsum, 0, (size_t)BATCH * SEQ * sizeof(float), stream);
    build_idx<<<BATCH, 256, 0, stream>>>(mask, idx, cnt, cntp);

    cast_bf16<<<NW / 8 / 256, 256, 0, stream>>>(Wq, wq, NW / 8);
    cast_bf16<<<NW / 8 / 256, 256, 0, stream>>>(Wk, wk, NW / 8);
    cast_bf16<<<NW / 8 / 256, 256, 0, stream>>>(Wv, wv, NW / 8);

    const dim3 blk(256);
    const dim3 gproj(DM / 128, SEQ / 128, BATCH);  // 8 x 16 x 8

    // K: gather+cast valid rows, project (M-limited)
    cast_gather<<<dim3(SEQ, BATCH), blk, 0, stream>>>(key_, xbuf, idx, cnt, cntp);
    gemm_bt<0><<<gproj, blk, 0, stream>>>(xbuf, wk, Kc, bk,
                                          DM, DM, DM, DM, 1.f, nullptr, cnt, cntp);
    // V: gather+cast valid rows, project transposed (M-limited)
    cast_gather<<<dim3(SEQ, BATCH), blk, 0, stream>>>(value, xbuf, idx, cnt, cntp);
    gemm_bt<1><<<gproj, blk, 0, stream>>>(xbuf, wv, Vtc, bv,
                                          DM, DM, DM, DM, 1.f, nullptr, cnt, cntp);
    // Q: plain cast + full projection
    cast_bf16<<<NE / 8 / 256, 256, 0, stream>>>(query, xbuf, NE / 8);
    gemm_bt<0><<<gproj, blk, 0, stream>>>(xbuf, wq, Qp, bq,
                                          DM, DM, DM, DM, 1.f, nullptr, nullptr, nullptr);

    // scores + exp + rowsum (N limited to cntp[b])
    gemm_bt<4><<<dim3(SEQ / 128, SEQ / 128, BATCH), blk, 0, stream>>>(
        Qp, Kc, probs, nullptr, DM, DM, SEQ, DM, 0.03125f, rowsum, cnt, cntp);

    // PV with fused 1/rowsum normalization (K limited to cntp[b])
    gemm_bt<3><<<dim3(DM / 128, SEQ / 128, BATCH), blk, 0, stream>>>(
        probs, Vtc, out, nullptr, SEQ, SEQ, DM, SEQ, 1.f, rowsum, cnt, cntp);
}

// Round 4
// 516.935 us; speedup vs baseline: 1.2520x; 1.0368x over previous
//
#include <hip/hip_runtime.h>

// SelfAttention B=8 S=2048 D=1024 fp32 -> fp32, bf16 MFMA internally.
// R4: (a) fp32->bf16 cast + mask-gather fused into projection A-staging
//     (no xbuf pass); (b) XCD batch-affinity block swizzle (batch = linear%8)
//     for L2 locality on all GEMMs.
// Pipeline:
//   build_idx; castW x3;
//   proj Q (fused cast) -> Qp; proj K (fused gather+cast) -> Kc;
//   proj V (fused gather+cast, transposed out) -> Vtc;
//   scores GEMM: p=(gn<cnt)?exp(s/32):0 -> bf16 probs + atomic rowsum
//   PV GEMM (K limited to cntp[b]), epilogue /rowsum -> fp32 out.
// GEMM core = m97-style: 128x128 tile, BK=32, 4 waves, 16x16x32 bf16 MFMA,
// 2-barrier K-loop; B staging async global_load_lds width=16.
// Workspace (~167MB): Qp[0,32M) Kc[32,64M) Vtc[64,96M) probs[96,160M)
//   weights[160,166M) rowsum/idx/cnt/cntp after.

#define BATCH 8
#define SEQ   2048
#define DM    1024

typedef __bf16 bf16x8 __attribute__((ext_vector_type(8)));
typedef float  f32x4  __attribute__((ext_vector_type(4)));
typedef unsigned short ushort8 __attribute__((ext_vector_type(8)));
typedef unsigned short ushort4v __attribute__((ext_vector_type(4)));

__device__ __forceinline__ unsigned short f2b(float f) {
    unsigned u = __builtin_bit_cast(unsigned, f);
    u += 0x7fffu + ((u >> 16) & 1u);   // round-to-nearest-even
    return (unsigned short)(u >> 16);
}

__device__ __forceinline__ void stage_async(const unsigned short* g,
                                            unsigned short* l) {
    __builtin_amdgcn_global_load_lds(
        (const __attribute__((address_space(1))) void*)g,
        (__attribute__((address_space(3))) void*)l, 16, 0, 0);
}

// fragment load + 4x4 MFMA for one BK=32 staged tile
__device__ __forceinline__ void frag_mfma(const unsigned short* As,
                                          const unsigned short* Bs,
                                          f32x4 acc[4][4], int waveM, int waveN,
                                          int quad, int l16) {
    bf16x8 af[4], bf[4];
#pragma unroll
    for (int i = 0; i < 4; ++i)
        af[i] = *(const bf16x8*)(As + (waveM * 64 + i * 16 + l16) * 32 + quad * 8);
#pragma unroll
    for (int j = 0; j < 4; ++j)
        bf[j] = *(const bf16x8*)(Bs + (waveN * 64 + j * 16 + l16) * 32 + quad * 8);
#pragma unroll
    for (int i = 0; i < 4; ++i)
#pragma unroll
        for (int j = 0; j < 4; ++j)
            acc[i][j] = __builtin_amdgcn_mfma_f32_16x16x32_bf16(
                af[i], bf[j], acc[i][j], 0, 0, 0);
}

// ---------------- per-batch mask compaction index ----------------
__global__ __launch_bounds__(256) void build_idx(
    const int* __restrict__ mask, int* __restrict__ idx,
    int* __restrict__ cnt, int* __restrict__ cntp) {
    const int b = blockIdx.x;
    const int* m = mask + b * SEQ;
    const int t = threadIdx.x;
    __shared__ int sums[256];
    int loc[8], s = 0;
#pragma unroll
    for (int u = 0; u < 8; ++u) { loc[u] = (m[t * 8 + u] != 0); s += loc[u]; }
    sums[t] = s;
    __syncthreads();
    for (int off = 1; off < 256; off <<= 1) {
        int v = (t >= off) ? sums[t - off] : 0;
        __syncthreads();
        sums[t] += v;
        __syncthreads();
    }
    int base = sums[t] - s;   // exclusive prefix
#pragma unroll
    for (int u = 0; u < 8; ++u)
        if (loc[u]) idx[b * SEQ + base++] = t * 8 + u;
    if (t == 255) {
        cnt[b] = sums[255];
        cntp[b] = (sums[255] + 127) & ~127;
    }
}

// ---------------- cast fp32 -> bf16 (weights only) ----------------
__global__ void cast_bf16(const float* __restrict__ src,
                          unsigned short* __restrict__ dst, int n8) {
    int i = blockIdx.x * blockDim.x + threadIdx.x;
    if (i >= n8) return;
    const f32x4* s4 = (const f32x4*)src;
    f32x4 a = s4[2 * i], b = s4[2 * i + 1];
    ushort8 o;
    o[0] = f2b(a[0]); o[1] = f2b(a[1]); o[2] = f2b(a[2]); o[3] = f2b(a[3]);
    o[4] = f2b(b[0]); o[5] = f2b(b[1]); o[6] = f2b(b[2]); o[7] = f2b(b[3]);
    ((ushort8*)dst)[i] = o;
}

// ------------- projection GEMM with fused cast(+gather) A-staging -------------
// C[M,N] = cast(X)[M,K] * W[N,K]^T + bias.  X fp32 (gathered rows if GATHER),
// W bf16 async-staged.  TROUT: write C^T -> C[b][n][m] (V path).
// grid (8,16,8); swizzle batch = linear&7.
template <bool GATHER, bool TROUT>
__global__ __launch_bounds__(256) void proj_gemm(
    const float* __restrict__ X, const unsigned short* __restrict__ W,
    unsigned short* __restrict__ C, const float* __restrict__ bias,
    const int* __restrict__ idx, const int* __restrict__ cnt,
    const int* __restrict__ cntp) {
    const int l = blockIdx.x + 8 * (blockIdx.y + 16 * blockIdx.z);
    const int bz = l & 7;
    const int i2 = l >> 3;            // 0..127
    const int n0 = (i2 & 7) * 128;
    const int m0 = (i2 >> 3) * 128;
    if (GATHER && m0 >= cntp[bz]) return;

    const int tid = threadIdx.x;
    const int wave = tid >> 6, lane = tid & 63;
    const int waveM = wave >> 1, waveN = wave & 1;
    const int quad = lane >> 4, l16 = lane & 15;

    __shared__ __align__(16) unsigned short As[128 * 32];
    __shared__ __align__(16) unsigned short Bs[128 * 32];
    f32x4 acc[4][4] = {};

    // A staging: thread -> (row = tid>>1, 16-col half)
    const int arow = tid >> 1;
    const int col0 = (tid & 1) * 16;
    const float* rp;
    if (GATHER) {
        const int gm = m0 + arow;
        rp = (gm < cnt[bz])
                 ? X + ((size_t)bz * SEQ + idx[bz * SEQ + gm]) * DM + col0
                 : nullptr;
    } else {
        rp = X + ((size_t)bz * SEQ + m0 + arow) * DM + col0;
    }
    unsigned short* lA = As + arow * 32 + col0;

    // B (weights) async staging
    const int sr = lane >> 2, sc = (lane & 3) * 8;
    const unsigned short* gB = W + (size_t)(n0 + wave * 32 + sr) * DM + sc;
    unsigned short* lB = Bs + (wave * 32 + sr) * 32 + sc;

    for (int kt = 0; kt < DM; kt += 32) {
        stage_async(gB + kt, lB);
        stage_async(gB + kt + 16 * DM, lB + 16 * 32);
        f32x4 a0 = {}, a1 = {}, a2 = {}, a3 = {};
        if (!GATHER || rp) {
            const f32x4* p4 = (const f32x4*)(rp + kt);
            a0 = p4[0]; a1 = p4[1]; a2 = p4[2]; a3 = p4[3];
        }
        ushort8 o0, o1;
        o0[0] = f2b(a0[0]); o0[1] = f2b(a0[1]); o0[2] = f2b(a0[2]); o0[3] = f2b(a0[3]);
        o0[4] = f2b(a1[0]); o0[5] = f2b(a1[1]); o0[6] = f2b(a1[2]); o0[7] = f2b(a1[3]);
        o1[0] = f2b(a2[0]); o1[1] = f2b(a2[1]); o1[2] = f2b(a2[2]); o1[3] = f2b(a2[3]);
        o1[4] = f2b(a3[0]); o1[5] = f2b(a3[1]); o1[6] = f2b(a3[2]); o1[7] = f2b(a3[3]);
        *(ushort8*)lA = o0;
        *(ushort8*)(lA + 8) = o1;
        __syncthreads();
        frag_mfma(As, Bs, acc, waveM, waveN, quad, l16);
        __syncthreads();
    }

    if (!TROUT) {
        unsigned short* Cb = C + (size_t)bz * SEQ * DM;
#pragma unroll
        for (int i = 0; i < 4; ++i) {
            const int gmb = m0 + waveM * 64 + i * 16 + quad * 4;
#pragma unroll
            for (int j = 0; j < 4; ++j) {
                const int gn = n0 + waveN * 64 + j * 16 + l16;
                const float bv = bias[gn];
#pragma unroll
                for (int r = 0; r < 4; ++r)
                    Cb[(size_t)(gmb + r) * DM + gn] = f2b(acc[i][j][r] + bv);
            }
        }
    } else {
        unsigned short* Cb = C + (size_t)bz * (size_t)DM * SEQ;
#pragma unroll
        for (int i = 0; i < 4; ++i) {
            const int gmb = m0 + waveM * 64 + i * 16 + quad * 4;  // compacted j
#pragma unroll
            for (int j = 0; j < 4; ++j) {
                const int gn = n0 + waveN * 64 + j * 16 + l16;
                const float bv = bias[gn];
                ushort4v o;
#pragma unroll
                for (int r = 0; r < 4; ++r) o[r] = f2b(acc[i][j][r] + bv);
                *(ushort4v*)(Cb + (size_t)gn * SEQ + gmb) = o;
            }
        }
    }
}

// ---------------- scores GEMM: probs = exp(Q.Kc^T/32), + rowsum ----------------
// grid (16,16,8); swizzle batch = linear&7 (one batch per XCD: Qp_b+Kc_b in L2).
__global__ __launch_bounds__(256) void scores_gemm(
    const unsigned short* __restrict__ Qp, const unsigned short* __restrict__ Kc,
    unsigned short* __restrict__ P, float* __restrict__ rowsum,
    const int* __restrict__ cnt, const int* __restrict__ cntp, float scale) {
    const int l = blockIdx.x + 16 * (blockIdx.y + 16 * blockIdx.z);
    const int bz = l & 7;
    const int i2 = l >> 3;            // 0..255
    const int n0 = (i2 & 15) * 128;
    const int m0 = (i2 >> 4) * 128;
    if (n0 >= cntp[bz]) return;

    const int tid = threadIdx.x;
    const int wave = tid >> 6, lane = tid & 63;
    const int waveM = wave >> 1, waveN = wave & 1;
    const int quad = lane >> 4, l16 = lane & 15;

    __shared__ __align__(16) unsigned short As[128 * 32];
    __shared__ __align__(16) unsigned short Bs[128 * 32];
    f32x4 acc[4][4] = {};

    const unsigned short* Ag = Qp + (size_t)bz * SEQ * DM;
    const unsigned short* Bg = Kc + (size_t)bz * SEQ * DM;
    const int sr = lane >> 2, sc = (lane & 3) * 8;
    const unsigned short* gA = Ag + (size_t)(m0 + wave * 32 + sr) * DM + sc;
    const unsigned short* gB = Bg + (size_t)(n0 + wave * 32 + sr) * DM + sc;
    unsigned short* lA = As + (wave * 32 + sr) * 32 + sc;
    unsigned short* lB = Bs + (wave * 32 + sr) * 32 + sc;

    for (int kt = 0; kt < DM; kt += 32) {
        stage_async(gA + kt, lA);
        stage_async(gA + kt + 16 * DM, lA + 16 * 32);
        stage_async(gB + kt, lB);
        stage_async(gB + kt + 16 * DM, lB + 16 * 32);
        __syncthreads();
        frag_mfma(As, Bs, acc, waveM, waveN, quad, l16);
        __syncthreads();
    }

    unsigned short* Cb = P + (size_t)bz * SEQ * SEQ;
    const int cn = cnt[bz];
#pragma unroll
    for (int i = 0; i < 4; ++i) {
        const int gmb = m0 + waveM * 64 + i * 16 + quad * 4;
        float rpart[4] = {0.f, 0.f, 0.f, 0.f};
#pragma unroll
        for (int j = 0; j < 4; ++j) {
            const int gn = n0 + waveN * 64 + j * 16 + l16;
            const float mv = (gn < cn) ? 1.0f : 0.0f;
#pragma unroll
            for (int r = 0; r < 4; ++r) {
                const float p = mv * __expf(acc[i][j][r] * scale);
                rpart[r] += p;
                Cb[(size_t)(gmb + r) * SEQ + gn] = f2b(p);
            }
        }
#pragma unroll
        for (int r = 0; r < 4; ++r) {
            float s = rpart[r];
            s += __shfl_xor(s, 1, 64);
            s += __shfl_xor(s, 2, 64);
            s += __shfl_xor(s, 4, 64);
            s += __shfl_xor(s, 8, 64);
            if (l16 == 0)
                atomicAdd(&rowsum[bz * SEQ + gmb + r], s);
        }
    }
}

// ---------------- PV GEMM: out = (P.Vtc^T) / rowsum ----------------
// grid (8,16,8); swizzle batch = linear&7.
__global__ __launch_bounds__(256) void pv_gemm(
    const unsigned short* __restrict__ P, const unsigned short* __restrict__ Vt,
    float* __restrict__ O, const float* __restrict__ rowsum,
    const int* __restrict__ cntp) {
    const int l = blockIdx.x + 8 * (blockIdx.y + 16 * blockIdx.z);
    const int bz = l & 7;
    const int i2 = l >> 3;            // 0..127
    const int n0 = (i2 & 7) * 128;
    const int m0 = (i2 >> 3) * 128;
    const int kend = cntp[bz];

    const int tid = threadIdx.x;
    const int wave = tid >> 6, lane = tid & 63;
    const int waveM = wave >> 1, waveN = wave & 1;
    const int quad = lane >> 4, l16 = lane & 15;

    __shared__ __align__(16) unsigned short As[128 * 32];
    __shared__ __align__(16) unsigned short Bs[128 * 32];
    f32x4 acc[4][4] = {};

    const unsigned short* Ag = P + (size_t)bz * SEQ * SEQ;
    const unsigned short* Bg = Vt + (size_t)bz * (size_t)DM * SEQ;
    const int sr = lane >> 2, sc = (lane & 3) * 8;
    const unsigned short* gA = Ag + (size_t)(m0 + wave * 32 + sr) * SEQ + sc;
    const unsigned short* gB = Bg + (size_t)(n0 + wave * 32 + sr) * SEQ + sc;
    unsigned short* lA = As + (wave * 32 + sr) * 32 + sc;
    unsigned short* lB = Bs + (wave * 32 + sr) * 32 + sc;

    for (int kt = 0; kt < kend; kt += 32) {
        stage_async(gA + kt, lA);
        stage_async(gA + kt + 16 * SEQ, lA + 16 * 32);
        stage_async(gB + kt, lB);
        stage_async(gB + kt + 16 * SEQ, lB + 16 * 32);
        __syncthreads();
        frag_mfma(As, Bs, acc, waveM, waveN, quad, l16);
        __syncthreads();
    }

    float* Cb = O + (size_t)bz * SEQ * DM;
#pragma unroll
    for (int i = 0; i < 4; ++i) {
        const int gmb = m0 + waveM * 64 + i * 16 + quad * 4;
        float inv[4];
#pragma unroll
        for (int r = 0; r < 4; ++r)
            inv[r] = 1.0f / rowsum[bz * SEQ + gmb + r];
#pragma unroll
        for (int j = 0; j < 4; ++j) {
            const int gn = n0 + waveN * 64 + j * 16 + l16;
#pragma unroll
            for (int r = 0; r < 4; ++r)
                Cb[(size_t)(gmb + r) * DM + gn] = acc[i][j][r] * inv[r];
        }
    }
}

extern "C" void kernel_launch(void* const* d_in, const int* in_sizes, int n_in,
                              void* d_out, int out_size, void* d_ws, size_t ws_size,
                              hipStream_t stream) {
    const float* query = (const float*)d_in[0];
    const float* key_  = (const float*)d_in[1];
    const float* value = (const float*)d_in[2];
    const int*   mask  = (const int*)d_in[3];
    const float* Wq = (const float*)d_in[4];
    const float* bq = (const float*)d_in[5];
    const float* Wk = (const float*)d_in[6];
    const float* bk = (const float*)d_in[7];
    const float* Wv = (const float*)d_in[8];
    const float* bv = (const float*)d_in[9];
    float* out = (float*)d_out;

    char* ws = (char*)d_ws;
    const size_t MB = 1024 * 1024;
    unsigned short* Qp    = (unsigned short*)(ws);             // 32MB
    unsigned short* Kc    = (unsigned short*)(ws + 32 * MB);   // 32MB
    unsigned short* Vtc   = (unsigned short*)(ws + 64 * MB);   // 32MB
    unsigned short* probs = (unsigned short*)(ws + 96 * MB);   // 64MB
    unsigned short* wq    = (unsigned short*)(ws + 160 * MB);  // 2MB
    unsigned short* wk    = (unsigned short*)(ws + 162 * MB);  // 2MB
    unsigned short* wv    = (unsigned short*)(ws + 164 * MB);  // 2MB
    float* rowsum = (float*)(ws + 166 * MB);                   // 64KB
    int*   idx    = (int*)(ws + 166 * MB + 64 * 1024);         // 64KB
    int*   cnt    = (int*)(ws + 166 * MB + 128 * 1024);        // 32B
    int*   cntp   = (int*)(ws + 166 * MB + 128 * 1024 + 64);   // 32B

    const int NW = DM * DM;  // 1048576

    hipMemsetAsync(rowsum, 0, (size_t)BATCH * SEQ * sizeof(float), stream);
    build_idx<<<BATCH, 256, 0, stream>>>(mask, idx, cnt, cntp);

    cast_bf16<<<NW / 8 / 256, 256, 0, stream>>>(Wq, wq, NW / 8);
    cast_bf16<<<NW / 8 / 256, 256, 0, stream>>>(Wk, wk, NW / 8);
    cast_bf16<<<NW / 8 / 256, 256, 0, stream>>>(Wv, wv, NW / 8);

    const dim3 blk(256);
    const dim3 gproj(8, 16, 8);

    proj_gemm<false, false><<<gproj, blk, 0, stream>>>(
        query, wq, Qp, bq, nullptr, nullptr, nullptr);
    proj_gemm<true, false><<<gproj, blk, 0, stream>>>(
        key_, wk, Kc, bk, idx, cnt, cntp);
    proj_gemm<true, true><<<gproj, blk, 0, stream>>>(
        value, wv, Vtc, bv, idx, cnt, cntp);

    scores_gemm<<<dim3(16, 16, 8), blk, 0, stream>>>(
        Qp, Kc, probs, rowsum, cnt, cntp, 0.03125f);

    pv_gemm<<<dim3(8, 16, 8), blk, 0, stream>>>(
        probs, Vtc, out, rowsum, cntp);
}